// Round 8
// baseline (363.923 us; speedup 1.0000x reference)
//
#include <hip/hip_runtime.h>

// Caser forward, MI355X. B=4096, L=5, D=128, NH=16, NV=4, T=100, FC1=752.
// R7 data: bank-conflict fix (3.7M->33K) was a null -> front is latency-
// bound at 16 waves/CU with 70% wait. R8: front = 512thr/block (32 waves/CU,
// lb(512,4) so VGPR<=128), P2b split into 32-thr groups (crit iters 160->80)
// + wave rotation to spread heavy waves across SIMDs. Tail: 16-lane-group
// dot (4 items/wave in flight, 4-step reduce instead of 6) + round prefetch.

constexpr int Bsz  = 4096;
constexpr int Lq   = 5;
constexpr int Dd   = 128;
constexpr int EP   = 132;   // padded emb row stride (floats)
constexpr int NHh  = 16;
constexpr int NVv  = 4;
constexpr int Tt   = 100;
constexpr int FC1  = 752;   // 4*128 + 16*15
constexpr int G    = 4;     // batch elems per block (kernel A)
constexpr int NTA  = 512;   // front block size (8 waves)
constexpr int NTB  = 256;   // tail block size

// P2b work table: eglt -> (l<<4 | t), packed so wave w (2 groups) is
// load-balanced: {5,1},{4,2},{4,2},{3,2},{3,2},{3,1},{1,1},{1,-}
__device__ __forceinline__ unsigned p2b_code(int eglt) {
    const unsigned long long lo = 0x2230214120401050ULL;
    const unsigned long long hi = 0x0014131211322331ULL;
    return (unsigned)(((eglt & 8) ? hi : lo) >> ((eglt & 7) * 8)) & 0xffu;
}

// ---------------- Kernel A: emb gather, convs, FC1 -> xc (B x 2D) ----------
__global__ __launch_bounds__(NTA, 4) void caser_front(
    const int* __restrict__ seq, const int* __restrict__ user,
    const float* __restrict__ item_table, const float* __restrict__ user_table,
    const float* __restrict__ Wv, const float* __restrict__ bv,
    const float* __restrict__ Wh, const float* __restrict__ bh,
    const float* __restrict__ W1, const float* __restrict__ b1,
    float* __restrict__ xc_ws)
{
    __shared__ float emb[G][Lq * EP];    // 10560 B, padded; reused as `part`
    __shared__ float z[G][FC1];          // 12032 B
    __shared__ float xc[G][2 * Dd];      // 4096 B -> 26688 B total

    const int tid  = threadIdx.x;
    const int lane = tid & 63;
    const int wv   = tid >> 6;
    const int b0   = blockIdx.x * G;
    float* embf = &emb[0][0];            // row gt at embf[gt*EP]

    // ---- phase 1: emb gather (G*5 rows of 128, coalesced per row) ----
    for (int idx = tid; idx < G * Lq * Dd; idx += NTA) {
        int gt  = idx >> 7;              // g*L + t
        int d   = idx & (Dd - 1);
        int row = seq[b0 * Lq + gt];
        embf[gt * EP + d] = item_table[row * Dd + d];
    }
    // uemb -> xc[g][128..255]
    for (int idx = tid; idx < G * Dd; idx += NTA) {
        int g = idx >> 7, d = idx & (Dd - 1);
        xc[g][Dd + d] = user_table[user[b0 + g] * Dd + d];
    }
    __syncthreads();

    // ---- phase 2a: vertical conv -> z[g][0..511] ----
    for (int idx = tid; idx < G * NVv * Dd; idx += NTA) {
        int g = idx >> 9;
        int v = (idx >> 7) & 3;
        int d = idx & (Dd - 1);
        float acc = bv[v];
        #pragma unroll
        for (int t = 0; t < Lq; ++t)
            acc = fmaf(emb[g][t * EP + d], Wv[v * Lq + t], acc);
        z[g][v * Dd + d] = acc;
    }

    // ---- phase 2b: horizontal convs -> z[g][512..751] ----
    // 32-thread group per (l,t): 16 f x 2 d-halves; combine via shfl_xor(16).
    // Wave rotation decorrelates heavy waves across blocks' SIMDs.
    {
        const int ewv  = (wv + (int)blockIdx.x) & 7;
        const int eglt = ewv * 2 + (lane >> 5);
        const unsigned code = p2b_code(eglt);
        if (code) {
            const int l    = code >> 4;
            const int t    = code & 15;
            const int half = (lane >> 4) & 1;
            const int f    = lane & 15;
            const int lout = Lq - l + 1;
            const int zoff = (l == 1) ? 0 : (l == 2) ? 80 : (l == 3) ? 144
                           : (l == 4) ? 192 : 224;
            const int dbase = half * 64;
            float acc[G] = {0.f, 0.f, 0.f, 0.f};
            const float* whb = Wh + (((l - 1) * NHh + f) * Lq) * Dd + dbase;
            const int niter = l * 16;            // (s, d4) flat, 16 f4/half
            float4 wc = *reinterpret_cast<const float4*>(whb);
            for (int it = 0; it < niter; ++it) {
                const int nx = it + 1;
                float4 wn = (nx < niter)
                    ? *reinterpret_cast<const float4*>(
                          whb + (nx >> 4) * Dd + (nx & 15) * 4)
                    : wc;
                const int s  = it >> 4;
                const int d4 = it & 15;
                const int eb = (t + s) * EP + dbase + d4 * 4;
                #pragma unroll
                for (int g = 0; g < G; ++g) {
                    float4 e = *reinterpret_cast<const float4*>(
                        &embf[g * Lq * EP + eb]);
                    acc[g] = fmaf(e.x, wc.x,
                             fmaf(e.y, wc.y,
                             fmaf(e.z, wc.z,
                             fmaf(e.w, wc.w, acc[g]))));
                }
                wc = wn;
            }
            #pragma unroll
            for (int g = 0; g < G; ++g)
                acc[g] += __shfl_xor(acc[g], 16);
            if (!half) {
                const float bias = bh[(l - 1) * NHh + f];
                #pragma unroll
                for (int g = 0; g < G; ++g)
                    z[g][NVv * Dd + zoff + f * lout + t]
                        = fmaxf(acc[g] + bias, 0.0f);
            }
        }
    }
    __syncthreads();

    // ---- phase 3: FC1  x = relu(z @ W1 + b1) ----
    // thread = (q = K-slab of 188, j = col): scalar coalesced W1 loads,
    // z reads wave-uniform (broadcast). Depth-2 chunk-4 prefetch.
    float* part = &embf[0];              // emb dead; 2048 <= 2640 floats
    {
        const int q = tid >> 7;          // 0..3
        const int j = tid & 127;
        const float* w1p = W1 + j;
        float acc[G] = {0.f, 0.f, 0.f, 0.f};
        const int i0 = q * 188;
        float c0 = w1p[(i0 + 0) * Dd];
        float c1 = w1p[(i0 + 1) * Dd];
        float c2 = w1p[(i0 + 2) * Dd];
        float c3 = w1p[(i0 + 3) * Dd];
        for (int i = i0; i < i0 + 188 - 4; i += 4) {
            float n0 = w1p[(i + 4) * Dd];
            float n1 = w1p[(i + 5) * Dd];
            float n2 = w1p[(i + 6) * Dd];
            float n3 = w1p[(i + 7) * Dd];
            #pragma unroll
            for (int g = 0; g < G; ++g) {
                float4 zz = *reinterpret_cast<const float4*>(&z[g][i]);
                acc[g] = fmaf(zz.x, c0, fmaf(zz.y, c1,
                         fmaf(zz.z, c2, fmaf(zz.w, c3, acc[g]))));
            }
            c0 = n0; c1 = n1; c2 = n2; c3 = n3;
        }
        {   // epilogue chunk
            const int i = i0 + 188 - 4;
            #pragma unroll
            for (int g = 0; g < G; ++g) {
                float4 zz = *reinterpret_cast<const float4*>(&z[g][i]);
                acc[g] = fmaf(zz.x, c0, fmaf(zz.y, c1,
                         fmaf(zz.z, c2, fmaf(zz.w, c3, acc[g]))));
            }
        }
        #pragma unroll
        for (int g = 0; g < G; ++g)
            part[(q * G + g) * Dd + j] = acc[g];
    }
    __syncthreads();
    if (tid < Dd) {
        #pragma unroll
        for (int g = 0; g < G; ++g) {
            float s = part[(0 * G + g) * Dd + tid]
                    + part[(1 * G + g) * Dd + tid]
                    + part[(2 * G + g) * Dd + tid]
                    + part[(3 * G + g) * Dd + tid];
            xc[g][tid] = fmaxf(s + b1[tid], 0.0f);
        }
    }
    __syncthreads();

    // ---- write xc to workspace, coalesced ----
    for (int idx = tid; idx < G * 2 * Dd; idx += NTA)
        xc_ws[b0 * 2 * Dd + idx] = xc[0][idx];
}

// ---------------- Kernel B: res[b][t] = dot(W2_table[item], xc[b]) + b2 ----
// 16-lane group per item: lane sub owns 16 floats of the 256-float row.
// 16 items in flight per block (4/wave); 4-step shuffle reduce; depth-1
// round prefetch keeps ~8KB of row loads in flight per wave.
__global__ __launch_bounds__(NTB, 6) void caser_tail(
    const int* __restrict__ items,
    const float* __restrict__ W2_table, const float* __restrict__ b2_table,
    const float* __restrict__ xc_ws, float* __restrict__ out)
{
    __shared__ int   s_items[Tt];
    __shared__ float s_b2[Tt];

    const int b    = blockIdx.x;
    const int tid  = threadIdx.x;
    const int lane = tid & 63;
    const int wv   = tid >> 6;
    const int grp  = lane >> 4;
    const int sub  = lane & 15;
    const int gidx = wv * 4 + grp;       // 0..15: item slot within a round

    if (tid < Tt) {
        int it = items[b * Tt + tid];
        s_items[tid] = it;
        s_b2[tid]    = b2_table[it];
    }
    // xc chunk for this lane: floats [sub*16, sub*16+16)
    const float4* xcp = reinterpret_cast<const float4*>(
        xc_ws + b * 2 * Dd + sub * 16);
    const float4 x0 = xcp[0], x1 = xcp[1], x2 = xcp[2], x3 = xcp[3];
    __syncthreads();

    float4 c0, c1, c2, c3;
    {   // preload round 0
        const float4* wp = reinterpret_cast<const float4*>(
            W2_table + (size_t)s_items[gidx] * (2 * Dd) + sub * 16);
        c0 = wp[0]; c1 = wp[1]; c2 = wp[2]; c3 = wp[3];
    }
    for (int r = 0; r < 6; ++r) {
        float4 n0, n1, n2, n3;
        if (r < 5) {
            const float4* wp = reinterpret_cast<const float4*>(
                W2_table + (size_t)s_items[(r + 1) * 16 + gidx] * (2 * Dd)
                + sub * 16);
            n0 = wp[0]; n1 = wp[1]; n2 = wp[2]; n3 = wp[3];
        }
        const int t = r * 16 + gidx;
        float p0 = fmaf(c0.x, x0.x, fmaf(c0.y, x0.y,
                   fmaf(c0.z, x0.z, c0.w * x0.w)));
        float p1 = fmaf(c1.x, x1.x, fmaf(c1.y, x1.y,
                   fmaf(c1.z, x1.z, c1.w * x1.w)));
        float p2 = fmaf(c2.x, x2.x, fmaf(c2.y, x2.y,
                   fmaf(c2.z, x2.z, c2.w * x2.w)));
        float p3 = fmaf(c3.x, x3.x, fmaf(c3.y, x3.y,
                   fmaf(c3.z, x3.z, c3.w * x3.w)));
        float v = (p0 + p1) + (p2 + p3);
        v += __shfl_xor(v, 1);
        v += __shfl_xor(v, 2);
        v += __shfl_xor(v, 4);
        v += __shfl_xor(v, 8);
        if (sub == 0) out[b * Tt + t] = v + s_b2[t];
        if (r < 5) { c0 = n0; c1 = n1; c2 = n2; c3 = n3; }
    }
    // epilogue: t = 96..99 handled by gidx 0..3 (wave 0)
    if (gidx < 4) {
        const int t = 96 + gidx;
        const float4* wp = reinterpret_cast<const float4*>(
            W2_table + (size_t)s_items[t] * (2 * Dd) + sub * 16);
        float4 w0 = wp[0], w1 = wp[1], w2 = wp[2], w3 = wp[3];
        float p0 = fmaf(w0.x, x0.x, fmaf(w0.y, x0.y,
                   fmaf(w0.z, x0.z, w0.w * x0.w)));
        float p1 = fmaf(w1.x, x1.x, fmaf(w1.y, x1.y,
                   fmaf(w1.z, x1.z, w1.w * x1.w)));
        float p2 = fmaf(w2.x, x2.x, fmaf(w2.y, x2.y,
                   fmaf(w2.z, x2.z, w2.w * x2.w)));
        float p3 = fmaf(w3.x, x3.x, fmaf(w3.y, x3.y,
                   fmaf(w3.z, x3.z, w3.w * x3.w)));
        float v = (p0 + p1) + (p2 + p3);
        v += __shfl_xor(v, 1);
        v += __shfl_xor(v, 2);
        v += __shfl_xor(v, 4);
        v += __shfl_xor(v, 8);
        if (sub == 0) out[b * Tt + t] = v + s_b2[t];
    }
}

extern "C" void kernel_launch(void* const* d_in, const int* in_sizes, int n_in,
                              void* d_out, int out_size, void* d_ws, size_t ws_size,
                              hipStream_t stream) {
    const int*   seq        = (const int*)  d_in[0];
    const int*   user       = (const int*)  d_in[1];
    const int*   items      = (const int*)  d_in[2];
    const float* item_table = (const float*)d_in[3];
    const float* user_table = (const float*)d_in[4];
    const float* Wv         = (const float*)d_in[5];
    const float* bv         = (const float*)d_in[6];
    const float* Wh         = (const float*)d_in[7];
    const float* bh         = (const float*)d_in[8];
    const float* W1         = (const float*)d_in[9];
    const float* b1         = (const float*)d_in[10];
    const float* W2_table   = (const float*)d_in[11];
    const float* b2_table   = (const float*)d_in[12];
    float* out   = (float*)d_out;
    float* xc_ws = (float*)d_ws;         // B * 2D floats = 4 MB

    caser_front<<<dim3(Bsz / G), dim3(NTA), 0, stream>>>(
        seq, user, item_table, user_table, Wv, bv, Wh, bh, W1, b1, xc_ws);
    caser_tail<<<dim3(Bsz), dim3(NTB), 0, stream>>>(
        items, W2_table, b2_table, xc_ws, out);
}